// Round 1
// baseline (929.914 us; speedup 1.0000x reference)
//
#include <hip/hip_runtime.h>

// Problem constants (B=2, D=64, H=W=96)
constexpr int B_    = 2;
constexpr int D_    = 64;
constexpr int N_    = 9216;      // 96*96
constexpr int ITERS = 4;

constexpr int MT      = 64;           // queries (m) per workgroup
constexpr int MB      = N_ / MT;      // 144 m-blocks
constexpr int KS      = 4;            // key-split factor
constexpr int KEYS_WG = N_ / KS;      // 2304 keys per workgroup
constexpr int KTILES  = KEYS_WG / (4 * 32); // 18 key tiles (of 32) per wave
constexpr int NWG     = B_ * MB * KS; // 1152 flash workgroups

constexpr float KBW  = 0.3f;
constexpr float STEP = 0.5f;

using short8   = __attribute__((ext_vector_type(8))) short;
using float16v = __attribute__((ext_vector_type(16))) float;
using ushort4v = __attribute__((ext_vector_type(4))) unsigned short;

__device__ __forceinline__ unsigned short f2bf(float f) {
  union { float f; unsigned u; } v; v.f = f;
  unsigned u = v.u;
  unsigned r = (u + 0x7fffu + ((u >> 16) & 1u)) >> 16;   // RNE
  return (unsigned short)r;
}
__device__ __forceinline__ float bf2f(unsigned short s) {
  union { unsigned u; float f; } v; v.u = ((unsigned)s) << 16;
  return v.f;
}

// ---------------------------------------------------------------------------
// prep: x_in (fp32 [b][d][n]) -> out slice 0 (copy), Xbf bf16 [b][d][n],
//       XT bf16 [b][n][d] (LDS transpose)
// grid: B_*MB blocks of 256
// ---------------------------------------------------------------------------
__global__ void prep_kernel(const float* __restrict__ xin, float* __restrict__ out,
                            unsigned short* __restrict__ XT,
                            unsigned short* __restrict__ Xbf)
{
  const int bx = blockIdx.x;
  const int nb = bx % MB, b = bx / MB;
  const int n0 = nb * 64;
  const int tid = threadIdx.x;
  __shared__ float tile[64 * 65];

  #pragma unroll
  for (int r = 0; r < 16; ++r) {
    int idx = r * 256 + tid;
    int d = idx >> 6, j = idx & 63;
    float v = xin[((size_t)b * 64 + d) * N_ + n0 + j];
    out[(((size_t)b * 5 + 0) * 64 + d) * N_ + n0 + j] = v;
    Xbf[((size_t)b * 64 + d) * N_ + n0 + j] = f2bf(v);
    tile[d * 65 + j] = v;
  }
  __syncthreads();
  #pragma unroll
  for (int r = 0; r < 16; ++r) {
    int idx = r * 256 + tid;
    int nl = idx >> 6, d = idx & 63;
    XT[((size_t)b * N_ + n0 + nl) * 64 + d] = f2bf(tile[d * 65 + nl]);
  }
}

// ---------------------------------------------------------------------------
// flash: one (b, m-block, key-split) per workgroup; 4 waves, each wave owns a
// disjoint key subset (no barriers in the K-loop). All X fragments are loaded
// directly from global (L2-resident bf16); only exp'd weights round-trip a
// per-wave LDS buffer (MFMA C-layout -> A-operand layout).
//
//   GEMM1: S[n'][m'] = sum_d XT[n0+n'][d] * XT[m0+m'][d]   (A=keys, B=queries)
//   GEMM2: accT[m][d] += sum_n W[m][n] * Xbf[d][n]         (A=weights, B=X)
// ---------------------------------------------------------------------------
__global__ void __launch_bounds__(256, 2) flash_kernel(
    const unsigned short* __restrict__ XT,
    const unsigned short* __restrict__ Xbf,
    float* __restrict__ pacc, float* __restrict__ pcs)
{
  const int bx   = blockIdx.x;
  const int ks   = bx & 3;
  const int mb   = (bx >> 2) % MB;
  const int b    = bx / (MB * KS);
  const int tid  = threadIdx.x;
  const int wave = tid >> 6, lane = tid & 63;
  const int c = lane & 31, h = lane >> 5;
  const int m0 = mb * MT;

  const unsigned short* XTb = XT  + (size_t)b * N_ * 64;
  const unsigned short* Xb  = Xbf + (size_t)b * 64 * N_;

  __shared__ unsigned short wbuf[4][64 * 40];  // per-wave W buffer, stride 40
  __shared__ float accbuf[64 * 65];
  __shared__ float csbuf[64];

  // resident query fragments: B-operand, lane&31 = m', k = h*8 + t (+16*kstep)
  short8 qf[2][4];
  #pragma unroll
  for (int mt = 0; mt < 2; ++mt)
    #pragma unroll
    for (int k = 0; k < 4; ++k)
      qf[mt][k] = *(const short8*)(XTb + (size_t)(m0 + mt * 32 + c) * 64 + k * 16 + h * 8);

  float16v zv;
  #pragma unroll
  for (int p = 0; p < 16; ++p) zv[p] = 0.f;
  float16v acc[2][2];
  acc[0][0] = zv; acc[0][1] = zv; acc[1][0] = zv; acc[1][1] = zv;
  float cs[2] = {0.f, 0.f};

  unsigned short* wb = &wbuf[wave][0];

  int n0 = ks * KEYS_WG + wave * 32;
  for (int t = 0; t < KTILES; ++t, n0 += 128) {
    // key fragments (A of GEMM1): lane&31 = n', k contiguous
    short8 af[4];
    #pragma unroll
    for (int k = 0; k < 4; ++k)
      af[k] = *(const short8*)(XTb + (size_t)(n0 + c) * 64 + k * 16 + h * 8);
    // X fragments (B of GEMM2): lane&31 = d', k = n contiguous
    short8 b2[2][2];
    #pragma unroll
    for (int k2 = 0; k2 < 2; ++k2)
      #pragma unroll
      for (int dt = 0; dt < 2; ++dt)
        b2[k2][dt] = *(const short8*)(Xb + (size_t)(dt * 32 + c) * N_ + n0 + k2 * 16 + h * 8);

    // GEMM1 + exp + store W to per-wave LDS in A-operand layout
    #pragma unroll
    for (int mt = 0; mt < 2; ++mt) {
      float16v S = zv;
      #pragma unroll
      for (int k = 0; k < 4; ++k)
        S = __builtin_amdgcn_mfma_f32_32x32x16_bf16(af[k], qf[mt][k], S, 0, 0, 0);
      // C-layout: col c = m' (lane&31), row n' = (p&3) + 8*(p>>2) + 4*h
      unsigned short wv[16];
      float lsum = 0.f;
      #pragma unroll
      for (int p = 0; p < 16; ++p) {
        float w = __expf(KBW * S[p]);
        unsigned short u = f2bf(w);
        wv[p] = u;
        lsum += bf2f(u);           // colsum from the *rounded* weights
      }
      cs[mt] += lsum;
      #pragma unroll
      for (int g = 0; g < 4; ++g) {
        ushort4v pk;
        pk[0] = wv[4 * g + 0]; pk[1] = wv[4 * g + 1];
        pk[2] = wv[4 * g + 2]; pk[3] = wv[4 * g + 3];
        // wbuf[m][n], m = mt*32+c, n = 8g + 4h + q  (q=0..3 contiguous)
        *(ushort4v*)(wb + (size_t)(mt * 32 + c) * 40 + g * 8 + h * 4) = pk;
      }
    }

    // GEMM2: accT[m][d] += W[m][n] * Xbf[d][n]
    #pragma unroll
    for (int k2 = 0; k2 < 2; ++k2) {
      short8 a2[2];
      #pragma unroll
      for (int mt = 0; mt < 2; ++mt)
        a2[mt] = *(short8*)(wb + (size_t)(mt * 32 + c) * 40 + k2 * 16 + h * 8);
      #pragma unroll
      for (int mt = 0; mt < 2; ++mt)
        #pragma unroll
        for (int dt = 0; dt < 2; ++dt)
          acc[mt][dt] = __builtin_amdgcn_mfma_f32_32x32x16_bf16(
              a2[mt], b2[k2][dt], acc[mt][dt], 0, 0, 0);
    }
  }

  // -------- epilogue: reduce 4 waves via LDS, write partials --------
  for (int i = tid; i < 64 * 65; i += 256) accbuf[i] = 0.f;
  if (tid < 64) csbuf[tid] = 0.f;
  __syncthreads();

  #pragma unroll
  for (int mt = 0; mt < 2; ++mt) {
    atomicAdd(&csbuf[mt * 32 + c], cs[mt]);
    #pragma unroll
    for (int dt = 0; dt < 2; ++dt)
      #pragma unroll
      for (int p = 0; p < 16; ++p) {
        int m = mt * 32 + (p & 3) + 8 * (p >> 2) + 4 * h;
        int d = dt * 32 + c;
        atomicAdd(&accbuf[m * 65 + d], acc[mt][dt][p]);
      }
  }
  __syncthreads();

  for (int i = tid; i < 4096; i += 256)
    pacc[(size_t)bx * 4096 + i] = accbuf[(i >> 6) * 65 + (i & 63)];
  if (tid < 64) pcs[(size_t)bx * 64 + tid] = csbuf[tid];
}

// ---------------------------------------------------------------------------
// combine: sum KS partials, normalize, blend with x_cur (= out slice t),
// write out slice t+1 + next iteration's Xbf / XT (bf16).
// grid: B_*MB blocks of 256
// ---------------------------------------------------------------------------
__global__ void combine_kernel(const float* __restrict__ pacc,
                               const float* __restrict__ pcs,
                               float* __restrict__ out,
                               unsigned short* __restrict__ XT,
                               unsigned short* __restrict__ Xbf, int t)
{
  const int bx = blockIdx.x;
  const int mb = bx % MB, b = bx / MB;
  const int m0 = mb * MT;
  const int tid = threadIdx.x;
  __shared__ float accs[64 * 65];
  __shared__ float xnew[64 * 65];
  __shared__ float cst[64];
  const int base = (b * MB + mb) * KS;

  #pragma unroll
  for (int r = 0; r < 16; ++r) {
    int idx = r * 256 + tid;
    int m = idx >> 6, d = idx & 63;
    float s = 0.f;
    #pragma unroll
    for (int k = 0; k < KS; ++k) s += pacc[(size_t)(base + k) * 4096 + idx];
    accs[m * 65 + d] = s;
  }
  if (tid < 64) {
    float cv = 0.f;
    #pragma unroll
    for (int k = 0; k < KS; ++k) cv += pcs[(size_t)(base + k) * 64 + tid];
    cst[tid] = cv;
  }
  __syncthreads();

  #pragma unroll
  for (int r = 0; r < 16; ++r) {
    int idx = r * 256 + tid;
    int m = idx & 63, d = idx >> 6;       // m fastest -> coalesced global n
    float a = accs[m * 65 + d];
    size_t obase = (((size_t)b * 5 + t) * 64 + d) * N_ + m0 + m;
    float xc = out[obase];
    float v = STEP * (a / cst[m]) + (1.f - STEP) * xc;
    out[obase + (size_t)64 * N_] = v;     // slice t+1
    Xbf[((size_t)b * 64 + d) * N_ + m0 + m] = f2bf(v);
    xnew[m * 65 + d] = v;
  }
  __syncthreads();

  #pragma unroll
  for (int r = 0; r < 16; ++r) {
    int idx = r * 256 + tid;
    int m = idx >> 6, d = idx & 63;       // d fastest -> coalesced XT row
    XT[((size_t)b * N_ + m0 + m) * 64 + d] = f2bf(xnew[m * 65 + d]);
  }
}

// ---------------------------------------------------------------------------
extern "C" void kernel_launch(void* const* d_in, const int* in_sizes, int n_in,
                              void* d_out, int out_size, void* d_ws, size_t ws_size,
                              hipStream_t stream)
{
  (void)in_sizes; (void)n_in; (void)out_size; (void)ws_size;
  const float* xin = (const float*)d_in[0];
  float* out = (float*)d_out;
  char* ws = (char*)d_ws;

  // workspace layout (23,887,872 B total):
  unsigned short* XT  = (unsigned short*)(ws);             //  2,359,296 B
  unsigned short* Xbf = (unsigned short*)(ws +  2359296);  //  2,359,296 B
  float*          pacc = (float*)(ws +  4718592);          // 18,874,368 B
  float*          pcs  = (float*)(ws + 23592960);          //    294,912 B

  prep_kernel<<<B_ * MB, 256, 0, stream>>>(xin, out, XT, Xbf);
  for (int t = 0; t < ITERS; ++t) {
    flash_kernel<<<NWG, 256, 0, stream>>>(XT, Xbf, pacc, pcs);
    combine_kernel<<<B_ * MB, 256, 0, stream>>>(pacc, pcs, out, XT, Xbf, t);
  }
}

// Round 2
// 926.917 us; speedup vs baseline: 1.0032x; 1.0032x over previous
//
#include <hip/hip_runtime.h>
#include <hip/hip_bf16.h>

// Problem constants (B=2, D=64, H=W=96)
constexpr int B_    = 2;
constexpr int D_    = 64;
constexpr int N_    = 9216;      // 96*96
constexpr int ITERS = 4;

constexpr int MT      = 64;           // queries (m) per workgroup
constexpr int MB      = N_ / MT;      // 144 m-blocks
constexpr int KS      = 4;            // key-split factor
constexpr int KEYS_WG = N_ / KS;      // 2304 keys per workgroup
constexpr int KTILES  = KEYS_WG / (4 * 32); // 18 key tiles (of 32) per wave
constexpr int NWG     = B_ * MB * KS; // 1152 flash workgroups

constexpr float KBW  = 0.3f;
constexpr float STEP = 0.5f;
constexpr float C2   = 0.43280851226668905f;  // KBW * log2(e)

using short8   = __attribute__((ext_vector_type(8))) short;
using float16v = __attribute__((ext_vector_type(16))) float;

__device__ __forceinline__ unsigned short f2bf(float f) {
  union { float f; unsigned u; } v; v.f = f;
  unsigned u = v.u;
  unsigned r = (u + 0x7fffu + ((u >> 16) & 1u)) >> 16;   // RNE
  return (unsigned short)r;
}

#if __has_builtin(__builtin_amdgcn_cvt_pk_bf16_f32)
typedef __attribute__((ext_vector_type(2))) __bf16 bf16x2;
__device__ __forceinline__ unsigned pk2bf(float a, float b) {
  bf16x2 r = __builtin_amdgcn_cvt_pk_bf16_f32(a, b);   // low <- a, high <- b, RNE
  union { bf16x2 h; unsigned u; } v; v.h = r; return v.u;
}
#else
__device__ __forceinline__ unsigned pk2bf(float a, float b) {
  return (unsigned)f2bf(a) | ((unsigned)f2bf(b) << 16);
}
#endif

// ---------------------------------------------------------------------------
// prep: x_in (fp32 [b][d][n]) -> out slice 0 (copy), Xbf bf16 [b][d][n],
//       XT bf16 [b][n][d] (LDS transpose)
// ---------------------------------------------------------------------------
__global__ void prep_kernel(const float* __restrict__ xin, float* __restrict__ out,
                            unsigned short* __restrict__ XT,
                            unsigned short* __restrict__ Xbf)
{
  const int bx = blockIdx.x;
  const int nb = bx % MB, b = bx / MB;
  const int n0 = nb * 64;
  const int tid = threadIdx.x;
  __shared__ float tile[64 * 65];

  #pragma unroll
  for (int r = 0; r < 16; ++r) {
    int idx = r * 256 + tid;
    int d = idx >> 6, j = idx & 63;
    float v = xin[((size_t)b * 64 + d) * N_ + n0 + j];
    out[(((size_t)b * 5 + 0) * 64 + d) * N_ + n0 + j] = v;
    Xbf[((size_t)b * 64 + d) * N_ + n0 + j] = f2bf(v);
    tile[d * 65 + j] = v;
  }
  __syncthreads();
  #pragma unroll
  for (int r = 0; r < 16; ++r) {
    int idx = r * 256 + tid;
    int nl = idx >> 6, d = idx & 63;
    XT[((size_t)b * N_ + n0 + nl) * 64 + d] = f2bf(tile[d * 65 + nl]);
  }
}

// ---------------------------------------------------------------------------
// flash: one (b, m-block, key-split) per workgroup; 4 waves, each wave owns a
// disjoint key subset (no barriers in the K-loop). X fragments come straight
// from L2; the exp'd weights move from MFMA C-layout to A-operand layout with
// 4 cross-lane (lane ^ 32) swaps per m-tile — no LDS in the K-loop at all.
//
//   GEMM1: S[n'][m'] = sum_d XT[n0+n'][d] * XT[m0+m'][d]
//   GEMM2: accT[m][d] += sum_n W[m][n] * Xbf[d][n]
// ---------------------------------------------------------------------------
__global__ void __launch_bounds__(256, 3) flash_kernel(
    const unsigned short* __restrict__ XT,
    const unsigned short* __restrict__ Xbf,
    float* __restrict__ pacc, float* __restrict__ pcs)
{
  const int bx   = blockIdx.x;
  const int ks   = bx & 3;
  const int mb   = (bx >> 2) % MB;
  const int b    = bx / (MB * KS);
  const int tid  = threadIdx.x;
  const int wave = tid >> 6, lane = tid & 63;
  const int c = lane & 31, h = lane >> 5;
  const int m0 = mb * MT;
  const int bpaddr = ((lane ^ 32) << 2);       // ds_bpermute byte index

  const unsigned short* XTb = XT  + (size_t)b * N_ * 64;
  const unsigned short* Xb  = Xbf + (size_t)b * 64 * N_;

  __shared__ float accbuf[64 * 65];
  __shared__ float csbuf[64];

  // resident query fragments: B-operand, lane&31 = m', k = h*8 + t (+16*kstep)
  short8 qf[2][4];
  #pragma unroll
  for (int mt = 0; mt < 2; ++mt)
    #pragma unroll
    for (int k = 0; k < 4; ++k)
      qf[mt][k] = *(const short8*)(XTb + (size_t)(m0 + mt * 32 + c) * 64 + k * 16 + h * 8);

  float16v zv;
  #pragma unroll
  for (int p = 0; p < 16; ++p) zv[p] = 0.f;
  float16v acc[2][2];
  acc[0][0] = zv; acc[0][1] = zv; acc[1][0] = zv; acc[1][1] = zv;
  float cs[2] = {0.f, 0.f};

  int n0 = ks * KEYS_WG + wave * 32;
  for (int t = 0; t < KTILES; ++t, n0 += 128) {
    // key fragments (A of GEMM1): lane&31 = n', k contiguous
    short8 af[4];
    #pragma unroll
    for (int k = 0; k < 4; ++k)
      af[k] = *(const short8*)(XTb + (size_t)(n0 + c) * 64 + k * 16 + h * 8);
    // X fragments (B of GEMM2): lane&31 = d', k = n contiguous
    short8 b2[2][2];
    #pragma unroll
    for (int k2 = 0; k2 < 2; ++k2)
      #pragma unroll
      for (int dt = 0; dt < 2; ++dt)
        b2[k2][dt] = *(const short8*)(Xb + (size_t)(dt * 32 + c) * N_ + n0 + k2 * 16 + h * 8);

    #pragma unroll
    for (int mt = 0; mt < 2; ++mt) {
      // ---- GEMM1 ----
      float16v S = zv;
      #pragma unroll
      for (int k = 0; k < 4; ++k)
        S = __builtin_amdgcn_mfma_f32_32x32x16_bf16(af[k], qf[mt][k], S, 0, 0, 0);

      // ---- exp + packed bf16 + colsum (from the rounded values) ----
      // C-layout: col m' = c, row n' = (p&3) + 8*(p>>2) + 4*h
      unsigned q[8];
      #pragma unroll
      for (int g = 0; g < 8; ++g) {
        float w0 = __builtin_amdgcn_exp2f(C2 * S[2 * g]);
        float w1 = __builtin_amdgcn_exp2f(C2 * S[2 * g + 1]);
        unsigned u = pk2bf(w0, w1);
        q[g] = u;
        union { unsigned u; float f; } lo, hi;
        lo.u = u << 16; hi.u = u & 0xffff0000u;
        cs[mt] += lo.f; cs[mt] += hi.f;
      }

      // ---- C-layout -> A-operand layout via lane^32 swaps ----
      // h=0 lane owns n-rows {4g..4g+3 -> q[2g],q[2g+1] at rows (g*8)..},
      // needs partner's q0,q1 (n4..7) and q4,q5 (n20..23);
      // h=1 needs partner's q2,q3 (n8..11) and q6,q7 (n24..27).
      unsigned s0 = h ? q[0] : q[2];
      unsigned s1 = h ? q[1] : q[3];
      unsigned s2 = h ? q[4] : q[6];
      unsigned s3 = h ? q[5] : q[7];
      unsigned r0 = (unsigned)__builtin_amdgcn_ds_bpermute(bpaddr, (int)s0);
      unsigned r1 = (unsigned)__builtin_amdgcn_ds_bpermute(bpaddr, (int)s1);
      unsigned r2 = (unsigned)__builtin_amdgcn_ds_bpermute(bpaddr, (int)s2);
      unsigned r3 = (unsigned)__builtin_amdgcn_ds_bpermute(bpaddr, (int)s3);

      union { unsigned d[4]; short8 s; } a20, a21;
      a20.d[0] = h ? r0   : q[0];
      a20.d[1] = h ? r1   : q[1];
      a20.d[2] = h ? q[2] : r0;
      a20.d[3] = h ? q[3] : r1;
      a21.d[0] = h ? r2   : q[4];
      a21.d[1] = h ? r3   : q[5];
      a21.d[2] = h ? q[6] : r2;
      a21.d[3] = h ? q[7] : r3;

      // ---- GEMM2: acc[m][d] += W[m][n] * X[d][n] ----
      #pragma unroll
      for (int dt = 0; dt < 2; ++dt)
        acc[mt][dt] = __builtin_amdgcn_mfma_f32_32x32x16_bf16(
            a20.s, b2[0][dt], acc[mt][dt], 0, 0, 0);
      #pragma unroll
      for (int dt = 0; dt < 2; ++dt)
        acc[mt][dt] = __builtin_amdgcn_mfma_f32_32x32x16_bf16(
            a21.s, b2[1][dt], acc[mt][dt], 0, 0, 0);
    }
  }

  // -------- epilogue: reduce 4 waves via LDS, write partials --------
  for (int i = tid; i < 64 * 65; i += 256) accbuf[i] = 0.f;
  if (tid < 64) csbuf[tid] = 0.f;
  __syncthreads();

  #pragma unroll
  for (int mt = 0; mt < 2; ++mt) {
    atomicAdd(&csbuf[mt * 32 + c], cs[mt]);
    #pragma unroll
    for (int dt = 0; dt < 2; ++dt)
      #pragma unroll
      for (int p = 0; p < 16; ++p) {
        int m = mt * 32 + (p & 3) + 8 * (p >> 2) + 4 * h;
        int d = dt * 32 + c;
        atomicAdd(&accbuf[m * 65 + d], acc[mt][dt][p]);
      }
  }
  __syncthreads();

  for (int i = tid; i < 4096; i += 256)
    pacc[(size_t)bx * 4096 + i] = accbuf[(i >> 6) * 65 + (i & 63)];
  if (tid < 64) pcs[(size_t)bx * 64 + tid] = csbuf[tid];
}

// ---------------------------------------------------------------------------
// combine: sum KS partials, normalize, blend with x_cur (= out slice t),
// write out slice t+1 + next iteration's Xbf / XT (bf16).
// ---------------------------------------------------------------------------
__global__ void combine_kernel(const float* __restrict__ pacc,
                               const float* __restrict__ pcs,
                               float* __restrict__ out,
                               unsigned short* __restrict__ XT,
                               unsigned short* __restrict__ Xbf, int t)
{
  const int bx = blockIdx.x;
  const int mb = bx % MB, b = bx / MB;
  const int m0 = mb * MT;
  const int tid = threadIdx.x;
  __shared__ float accs[64 * 65];
  __shared__ float xnew[64 * 65];
  __shared__ float cst[64];
  const int base = (b * MB + mb) * KS;

  #pragma unroll
  for (int r = 0; r < 16; ++r) {
    int idx = r * 256 + tid;
    int m = idx >> 6, d = idx & 63;
    float s = 0.f;
    #pragma unroll
    for (int k = 0; k < KS; ++k) s += pacc[(size_t)(base + k) * 4096 + idx];
    accs[m * 65 + d] = s;
  }
  if (tid < 64) {
    float cv = 0.f;
    #pragma unroll
    for (int k = 0; k < KS; ++k) cv += pcs[(size_t)(base + k) * 64 + tid];
    cst[tid] = cv;
  }
  __syncthreads();

  #pragma unroll
  for (int r = 0; r < 16; ++r) {
    int idx = r * 256 + tid;
    int m = idx & 63, d = idx >> 6;       // m fastest -> coalesced global n
    float a = accs[m * 65 + d];
    size_t obase = (((size_t)b * 5 + t) * 64 + d) * N_ + m0 + m;
    float xc = out[obase];
    float v = STEP * (a / cst[m]) + (1.f - STEP) * xc;
    out[obase + (size_t)64 * N_] = v;     // slice t+1
    Xbf[((size_t)b * 64 + d) * N_ + m0 + m] = f2bf(v);
    xnew[m * 65 + d] = v;
  }
  __syncthreads();

  #pragma unroll
  for (int r = 0; r < 16; ++r) {
    int idx = r * 256 + tid;
    int m = idx >> 6, d = idx & 63;       // d fastest -> coalesced XT row
    XT[((size_t)b * N_ + m0 + m) * 64 + d] = f2bf(xnew[m * 65 + d]);
  }
}

// ---------------------------------------------------------------------------
extern "C" void kernel_launch(void* const* d_in, const int* in_sizes, int n_in,
                              void* d_out, int out_size, void* d_ws, size_t ws_size,
                              hipStream_t stream)
{
  (void)in_sizes; (void)n_in; (void)out_size; (void)ws_size;
  const float* xin = (const float*)d_in[0];
  float* out = (float*)d_out;
  char* ws = (char*)d_ws;

  // workspace layout (23,887,872 B total):
  unsigned short* XT  = (unsigned short*)(ws);             //  2,359,296 B
  unsigned short* Xbf = (unsigned short*)(ws +  2359296);  //  2,359,296 B
  float*          pacc = (float*)(ws +  4718592);          // 18,874,368 B
  float*          pcs  = (float*)(ws + 23592960);          //    294,912 B

  prep_kernel<<<B_ * MB, 256, 0, stream>>>(xin, out, XT, Xbf);
  for (int t = 0; t < ITERS; ++t) {
    flash_kernel<<<NWG, 256, 0, stream>>>(XT, Xbf, pacc, pcs);
    combine_kernel<<<B_ * MB, 256, 0, stream>>>(pacc, pcs, out, XT, Xbf, t);
  }
}